// Round 6
// baseline (418.775 us; speedup 1.0000x reference)
//
#include <hip/hip_runtime.h>
#include <stdint.h>

#define GRID_Z 10
#define GRID_Y 400
#define GRID_X 352
#define NGRID (GRID_Z * GRID_Y * GRID_X)   // 1,408,000
#define NVOX 200000
#define CCH 128
#define MROI 64
#define GXD 64
#define GYD 32
#define GZD 4
#define GCELLS 8192                         // GXD*GYD*GZD
#define NTAPS 147                           // 7*7*3
#define FPAD 132                            // feat LDS row pitch (128+4)
#define TROWS 32                            // voxel rows per tile
#define NSLC 12                             // slices per ROI -> 768 blocks = 3/CU
#define ABLK 4                              // argfin blocks per ROI

// Recompute a grid cell's world xyz exactly like the reference (fp32, no fma
// contraction so floor() boundaries match XLA's mul+add evaluation).
__device__ __forceinline__ void cell_xyz(const float* __restrict__ roi, int g,
                                         float& X, float& Y, float& Z) {
#pragma clang fp contract(off)
    int iz = g & 3;
    int iy = (g >> 2) & 31;
    int ix = g >> 7;
    float bx = roi[3] * 2.0f;   // EXTEND on x,y dims
    float by = roi[4] * 2.0f;
    float bz = roi[5];
    float lx = (ix + 0.5f) / 64.0f * bx - bx / 2.0f;
    float ly = (iy + 0.5f) / 32.0f * by - by / 2.0f;
    float lz = (iz + 0.5f) / 4.0f  * bz - bz / 2.0f;
    float c = cosf(roi[6]);
    float s = sinf(roi[6]);
    X = lx * c + ly * (-s) + roi[0];
    Y = lx * s + ly * c    + roi[1];
    Z = lz + roi[2];
}

__device__ __forceinline__ int cell_to_pidx(const float* __restrict__ roi, int g,
                                            const int* __restrict__ v2p) {
#pragma clang fp contract(off)
    float X, Y, Z;
    cell_xyz(roi, g, X, Y, Z);
    float fx = floorf((X - 0.0f)     / 0.05f);
    float fy = floorf((Y - (-40.0f)) / 0.05f);
    float fz = floorf((Z - (-3.0f))  / 0.1f);
    int cx = (int)floorf(fx / 4.0f);
    int cy = (int)floorf(fy / 4.0f);
    int cz = (int)floorf(fz / 4.0f);
    int p = -1;
    if (cz >= 0 && cz < GRID_Z && cy >= 0 && cy < GRID_Y && cx >= 0 && cx < GRID_X)
        p = v2p[(cz * GRID_Y + cy) * GRID_X + cx];
    return p;
}

// ---------------- phase kernels (stream-ordered) ----------------
__global__ void k_scatter(const int* __restrict__ vcoords, int* __restrict__ v2p,
                          int* __restrict__ cnt) {
    int i = blockIdx.x * 256 + threadIdx.x;
    if (blockIdx.x == 0 && threadIdx.x < MROI) cnt[threadIdx.x] = 0;
    if (i >= NVOX) return;
    int z = vcoords[i * 4 + 1];
    int y = vcoords[i * 4 + 2];
    int x = vcoords[i * 4 + 3];
    atomicMax(&v2p[(z * GRID_Y + y) * GRID_X + x], i);
}

__global__ void k_zbest(unsigned long long* __restrict__ best, unsigned* __restrict__ done) {
    if (threadIdx.x < MROI) best[threadIdx.x] = 0ull;
    if (threadIdx.x == 0) *done = 0u;
}

__global__ void k_build(const float* __restrict__ rois, const int* __restrict__ v2p,
                        unsigned* __restrict__ list, int* __restrict__ cnt) {
    int g = blockIdx.x * 256 + threadIdx.x;
    int m = blockIdx.y;
    int lane = threadIdx.x & 63;
    int p = cell_to_pidx(rois + m * 7, g, v2p);
    bool v = p >= 0;
    unsigned long long bal = __ballot(v);
    int nset = __popcll(bal);
    int base = 0;
    if (lane == 0 && nset) base = atomicAdd(&cnt[m], nset);
    base = __shfl(base, 0, 64);
    if (v) {
        int pos = __popcll(bal & ((1ull << lane) - 1ull));
        list[m * GCELLS + base + pos] = ((unsigned)p << 13) | (unsigned)g;
    }
}

// dots: 512-thread blocks, k-split across wave halves (waves 0-3: ch 0-63,
// waves 4-7: ch 64-127). Same 50 KB LDS per block -> 24 waves/CU (was 12).
// Per-thread tile: R1 measured-best 4 rows x 5 taps.
__global__ __launch_bounds__(512, 6) void k_dots(
        const float* __restrict__ vfeat, const float* __restrict__ fproto,
        const unsigned* __restrict__ list, const int* __restrict__ cnt,
        float* __restrict__ partial) {
    __shared__ float    sscore[GCELLS];        // 32 KB private score tile
    __shared__ float    sfeat[TROWS * FPAD];   // 16.9 KB staged feature rows
    __shared__ unsigned sg[TROWS];

    const int m    = blockIdx.y;
    const int tid  = threadIdx.x;
    const int w    = tid >> 6;                 // wave 0..7
    const int lane = tid & 63;
    const int vi   = lane & 7;                 // rows vi + 8a, a=0..3
    const int ti   = (lane >> 3) & 7;
    const int wq   = w & 3;                    // tap-wave 0..3
    const int kb   = (w >> 2) << 6;            // k-half base: 0 or 64
    const int n    = cnt[m];
    const unsigned* lst = list + m * GCELLS;
    const int tbase = wq * 40 + ti;            // taps: tbase + 8b, b=0..4

    int tkx[5], tky[5], tkz[5], tok[5];
    const float* wp[5];
    #pragma unroll
    for (int b = 0; b < 5; ++b) {
        int t = tbase + 8 * b;
        tok[b] = t < NTAPS;
        int tc = tok[b] ? t : (NTAPS - 1);
        int kx  = tc / 21;
        int rem = tc - kx * 21;
        tkx[b] = kx; tky[b] = rem / 3; tkz[b] = rem - tky[b] * 3;
        wp[b] = fproto + tc * CCH + kb;
    }
    {   // zero the private score tile
        float4* s4 = (float4*)sscore;
        #pragma unroll
        for (int i = 0; i < GCELLS / 4 / 512; ++i)
            s4[tid + 512 * i] = make_float4(0.f, 0.f, 0.f, 0.f);
    }
    for (int vt0 = blockIdx.x * TROWS; vt0 < n; vt0 += TROWS * NSLC) {
        __syncthreads();                       // score-zero / prior deposits done
        {   // stage 32 feat rows: 16 threads per row, 8 floats each
            int r = tid >> 4, q = tid & 15, v = vt0 + r;
            unsigned e = 0xFFFFFFFFu;
            if (v < n) e = lst[v];
            if (q == 0) sg[r] = e;
            if (e != 0xFFFFFFFFu) {
                int p = (int)(e >> 13);
                const float4* src = (const float4*)(vfeat + (size_t)p * CCH) + q * 2;
                float4* drow = (float4*)(sfeat + r * FPAD + q * 8);
                drow[0] = src[0];
                drow[1] = src[1];
            }
        }
        __syncthreads();
        float acc[4][5];
        #pragma unroll
        for (int a = 0; a < 4; ++a)
            #pragma unroll
            for (int b = 0; b < 5; ++b) acc[a][b] = 0.0f;
        #pragma unroll 1
        for (int kk = 0; kk < CCH / 2; kk += 4) {
            const int k = kb + kk;
            float4 f[4];
            #pragma unroll
            for (int a = 0; a < 4; ++a)
                f[a] = *(const float4*)&sfeat[(vi + 8 * a) * FPAD + k];
            float4 wv[5];
            #pragma unroll
            for (int b = 0; b < 5; ++b)
                wv[b] = *(const float4*)(wp[b] + kk);
            #pragma unroll
            for (int a = 0; a < 4; ++a)
                #pragma unroll
                for (int b = 0; b < 5; ++b) {
                    acc[a][b] = fmaf(f[a].x, wv[b].x, acc[a][b]);
                    acc[a][b] = fmaf(f[a].y, wv[b].y, acc[a][b]);
                    acc[a][b] = fmaf(f[a].z, wv[b].z, acc[a][b]);
                    acc[a][b] = fmaf(f[a].w, wv[b].w, acc[a][b]);
                }
        }
        #pragma unroll
        for (int a = 0; a < 4; ++a) {
            unsigned e = sg[vi + 8 * a];
            if (e == 0xFFFFFFFFu) continue;
            int g  = (int)(e & 8191u);
            int gx = g >> 7, gy = (g >> 2) & 31, gz = g & 3;
            #pragma unroll
            for (int b = 0; b < 5; ++b) {
                if (!tok[b]) continue;
                int cx = gx - (tkx[b] - 3);
                int cy = gy - (tky[b] - 3);
                int cz = gz - (tkz[b] - 1);
                if ((unsigned)cx < (unsigned)GXD && (unsigned)cy < (unsigned)GYD &&
                    (unsigned)cz < (unsigned)GZD)
                    atomicAdd(&sscore[(cx << 7) | (cy << 2) | cz], acc[a][b]);
            }
        }
    }
    __syncthreads();                           // all waves' deposits done
    {   // coalesced partial writeback (covers every cell)
        float* dst = partial + ((size_t)m * NSLC + blockIdx.x) * GCELLS;
        const float4* s4 = (const float4*)sscore;
        float4* d4 = (float4*)dst;
        #pragma unroll
        for (int i = 0; i < GCELLS / 4 / 512; ++i)
            d4[tid + 512 * i] = s4[tid + 512 * i];
    }
}

// argfin: 4 blocks/ROI sum the 12 partials over a 2048-cell chunk, block-argmax,
// u64 atomicMax into best[m]; globally-last block writes all 64 outputs.
__global__ __launch_bounds__(256) void k_argfin(
        const float* __restrict__ partial, const float* __restrict__ rois,
        const float* __restrict__ pbox, unsigned long long* __restrict__ best,
        unsigned* __restrict__ done, float* __restrict__ out) {
    __shared__ unsigned long long red[256];
    __shared__ unsigned lastflag;
    const int tid = threadIdx.x;
    const int m = blockIdx.y;
    const float* base = partial + (size_t)m * NSLC * GCELLS;
    const int c0 = blockIdx.x * (GCELLS / ABLK);
    unsigned long long bk = 0ull;
    #pragma unroll
    for (int i = 0; i < GCELLS / ABLK / 256; ++i) {
        int c = c0 + tid + 256 * i;
        float v = 0.0f;
        #pragma unroll
        for (int s = 0; s < NSLC; ++s) v += base[s * GCELLS + c];
        unsigned ub  = __float_as_uint(v);
        unsigned key = (ub & 0x80000000u) ? ~ub : (ub | 0x80000000u);  // order-preserving
        unsigned long long pk =
            ((unsigned long long)key << 32) | (unsigned)(GCELLS - 1 - c);  // ties -> smallest g
        bk = bk > pk ? bk : pk;
    }
    red[tid] = bk;
    __syncthreads();
    for (int st = 128; st > 0; st >>= 1) {
        if (tid < st) {
            unsigned long long o = red[tid + st];
            if (o > red[tid]) red[tid] = o;
        }
        __syncthreads();
    }
    if (tid == 0) {
        atomicMax(&best[m], red[0]);
        __threadfence();                       // publish before signalling done
        unsigned d = atomicAdd(done, 1u);
        lastflag = (d == ABLK * MROI - 1u);
    }
    __syncthreads();
    if (lastflag && tid < MROI) {
        // atomic read -> sees all prior atomicMax on the same address
        unsigned long long bv = atomicMax(&best[tid], 0ull);
        int g = (GCELLS - 1) - (int)(unsigned)(bv & 0xFFFFFFFFu);
        float X, Y, Z;
        cell_xyz(rois + tid * 7, g, X, Y, Z);
        out[tid * 7 + 0] = X;
        out[tid * 7 + 1] = Y;
        out[tid * 7 + 2] = Z;
        out[tid * 7 + 3] = pbox[3];
        out[tid * 7 + 4] = pbox[4];
        out[tid * 7 + 5] = pbox[5];
        out[tid * 7 + 6] = pbox[6];
    }
}

extern "C" void kernel_launch(void* const* d_in, const int* in_sizes, int n_in,
                              void* d_out, int out_size, void* d_ws, size_t ws_size,
                              hipStream_t stream) {
    const float* rois    = (const float*)d_in[0];
    const float* pbox    = (const float*)d_in[1];
    const float* vfeat   = (const float*)d_in[2];
    const float* fproto  = (const float*)d_in[3];
    const int*   vcoords = (const int*)d_in[4];
    float* out = (float*)d_out;

    // ws layout: v2p | list | partial(12 slices) | best(64 u64) | cnt(64) | done(1)
    int*      v2p     = (int*)d_ws;                              // NGRID ints
    unsigned* list    = (unsigned*)(v2p + NGRID);                // MROI*GCELLS
    float*    partial = (float*)(list + (size_t)MROI * GCELLS);  // 12*MROI*GCELLS floats
    unsigned long long* best =
        (unsigned long long*)(partial + (size_t)NSLC * MROI * GCELLS);
    int*      cnt  = (int*)(best + MROI);                        // 64 ints
    unsigned* done = (unsigned*)(cnt + MROI);                    // 1 uint

    hipMemsetAsync(v2p, 0xFF, (size_t)NGRID * 4, stream);
    k_zbest  <<<1, 64, 0, stream>>>(best, done);
    k_scatter<<<(NVOX + 255) / 256, 256, 0, stream>>>(vcoords, v2p, cnt);
    k_build  <<<dim3(GCELLS / 256, MROI), 256, 0, stream>>>(rois, v2p, list, cnt);
    k_dots   <<<dim3(NSLC, MROI), 512, 0, stream>>>(vfeat, fproto, list, cnt, partial);
    k_argfin <<<dim3(ABLK, MROI), 256, 0, stream>>>(partial, rois, pbox, best, done, out);
}

// Round 7
// 360.763 us; speedup vs baseline: 1.1608x; 1.1608x over previous
//
#include <hip/hip_runtime.h>
#include <stdint.h>

#define GRID_Z 10
#define GRID_Y 400
#define GRID_X 352
#define NGRID (GRID_Z * GRID_Y * GRID_X)   // 1,408,000
#define NVOX 200000
#define CCH 128
#define MROI 64
#define GXD 64
#define GYD 32
#define GZD 4
#define GCELLS 8192                         // GXD*GYD*GZD
#define NTAPS 147                           // 7*7*3
#define FPAD 132                            // feat LDS row pitch (128+4)
#define TROWS 32                            // voxel rows per tile
#define NSLC 12                             // slices per ROI -> 768 blocks
#define ABLK 4                              // argfin blocks per ROI

// Recompute a grid cell's world xyz exactly like the reference (fp32, no fma
// contraction so floor() boundaries match XLA's mul+add evaluation).
__device__ __forceinline__ void cell_xyz(const float* __restrict__ roi, int g,
                                         float& X, float& Y, float& Z) {
#pragma clang fp contract(off)
    int iz = g & 3;
    int iy = (g >> 2) & 31;
    int ix = g >> 7;
    float bx = roi[3] * 2.0f;   // EXTEND on x,y dims
    float by = roi[4] * 2.0f;
    float bz = roi[5];
    float lx = (ix + 0.5f) / 64.0f * bx - bx / 2.0f;
    float ly = (iy + 0.5f) / 32.0f * by - by / 2.0f;
    float lz = (iz + 0.5f) / 4.0f  * bz - bz / 2.0f;
    float c = cosf(roi[6]);
    float s = sinf(roi[6]);
    X = lx * c + ly * (-s) + roi[0];
    Y = lx * s + ly * c    + roi[1];
    Z = lz + roi[2];
}

__device__ __forceinline__ int cell_to_pidx(const float* __restrict__ roi, int g,
                                            const int* __restrict__ v2p) {
#pragma clang fp contract(off)
    float X, Y, Z;
    cell_xyz(roi, g, X, Y, Z);
    float fx = floorf((X - 0.0f)     / 0.05f);
    float fy = floorf((Y - (-40.0f)) / 0.05f);
    float fz = floorf((Z - (-3.0f))  / 0.1f);
    int cx = (int)floorf(fx / 4.0f);
    int cy = (int)floorf(fy / 4.0f);
    int cz = (int)floorf(fz / 4.0f);
    int p = -1;
    if (cz >= 0 && cz < GRID_Z && cy >= 0 && cy < GRID_Y && cx >= 0 && cx < GRID_X)
        p = v2p[(cz * GRID_Y + cy) * GRID_X + cx];
    return p;
}

// ---------------- phase kernels (stream-ordered) ----------------
__global__ void k_scatter(const int* __restrict__ vcoords, int* __restrict__ v2p,
                          int* __restrict__ cnt) {
    int i = blockIdx.x * 256 + threadIdx.x;
    if (blockIdx.x == 0 && threadIdx.x < MROI) cnt[threadIdx.x] = 0;
    if (i >= NVOX) return;
    int z = vcoords[i * 4 + 1];
    int y = vcoords[i * 4 + 2];
    int x = vcoords[i * 4 + 3];
    atomicMax(&v2p[(z * GRID_Y + y) * GRID_X + x], i);
}

__global__ void k_zbest(unsigned long long* __restrict__ best, unsigned* __restrict__ done) {
    if (threadIdx.x < MROI) best[threadIdx.x] = 0ull;
    if (threadIdx.x == 0) *done = 0u;
}

__global__ void k_build(const float* __restrict__ rois, const int* __restrict__ v2p,
                        unsigned* __restrict__ list, int* __restrict__ cnt) {
    int g = blockIdx.x * 256 + threadIdx.x;
    int m = blockIdx.y;
    int lane = threadIdx.x & 63;
    int p = cell_to_pidx(rois + m * 7, g, v2p);
    bool v = p >= 0;
    unsigned long long bal = __ballot(v);
    int nset = __popcll(bal);
    int base = 0;
    if (lane == 0 && nset) base = atomicAdd(&cnt[m], nset);
    base = __shfl(base, 0, 64);
    if (v) {
        int pos = __popcll(bal & ((1ull << lane) - 1ull));
        list[m * GCELLS + base + pos] = ((unsigned)p << 13) | (unsigned)g;
    }
}

// dots: 512-thread blocks, 8 waves. Row-split: waves 0-3 own rows 0-15,
// waves 4-7 own rows 16-31. Tap map per 4-wave group = R1 measured-best
// (tbase = wq*40 + ti, 5 taps/thread). Per-thread: acc[2][5] -> ~70 VGPR,
// no launch_bounds min-waves arg (R6 lesson: it forces spills).
// Same 50 KB LDS -> 3 blocks/CU = 24 waves/CU (was 12).
__global__ __launch_bounds__(512) void k_dots(
        const float* __restrict__ vfeat, const float* __restrict__ fproto,
        const unsigned* __restrict__ list, const int* __restrict__ cnt,
        float* __restrict__ partial) {
    __shared__ float    sscore[GCELLS];        // 32 KB private score tile
    __shared__ float    sfeat[TROWS * FPAD];   // 16.9 KB staged feature rows
    __shared__ unsigned sg[TROWS];

    const int m    = blockIdx.y;
    const int tid  = threadIdx.x;
    const int w    = tid >> 6;                 // wave 0..7
    const int lane = tid & 63;
    const int vi   = lane & 7;
    const int ti   = (lane >> 3) & 7;
    const int wq   = w & 3;                    // tap-wave 0..3
    const int h16  = (w >> 2) << 4;            // row-half base: 0 or 16
    const int n    = cnt[m];
    const unsigned* lst = list + m * GCELLS;
    const int tbase = wq * 40 + ti;            // taps: tbase + 8b, b=0..4

    int tkx[5], tky[5], tkz[5], tok[5];
    const float* wp[5];
    #pragma unroll
    for (int b = 0; b < 5; ++b) {
        int t = tbase + 8 * b;
        tok[b] = t < NTAPS;
        int tc = tok[b] ? t : (NTAPS - 1);
        int kx  = tc / 21;
        int rem = tc - kx * 21;
        tkx[b] = kx; tky[b] = rem / 3; tkz[b] = rem - tky[b] * 3;
        wp[b] = fproto + tc * CCH;
    }
    {   // zero the private score tile
        float4* s4 = (float4*)sscore;
        #pragma unroll
        for (int i = 0; i < GCELLS / 4 / 512; ++i)
            s4[tid + 512 * i] = make_float4(0.f, 0.f, 0.f, 0.f);
    }
    for (int vt0 = blockIdx.x * TROWS; vt0 < n; vt0 += TROWS * NSLC) {
        __syncthreads();                       // score-zero / prior deposits done
        {   // stage 32 feat rows: 16 threads per row, 8 floats each
            int r = tid >> 4, q = tid & 15, v = vt0 + r;
            unsigned e = 0xFFFFFFFFu;
            if (v < n) e = lst[v];
            if (q == 0) sg[r] = e;
            if (e != 0xFFFFFFFFu) {
                int p = (int)(e >> 13);
                const float4* src = (const float4*)(vfeat + (size_t)p * CCH) + q * 2;
                float4* drow = (float4*)(sfeat + r * FPAD + q * 8);
                drow[0] = src[0];
                drow[1] = src[1];
            }
        }
        __syncthreads();
        float acc[2][5];
        #pragma unroll
        for (int a = 0; a < 2; ++a)
            #pragma unroll
            for (int b = 0; b < 5; ++b) acc[a][b] = 0.0f;
        #pragma unroll 1
        for (int k = 0; k < CCH; k += 4) {
            float4 f[2];
            #pragma unroll
            for (int a = 0; a < 2; ++a)
                f[a] = *(const float4*)&sfeat[(h16 + vi + 8 * a) * FPAD + k];
            float4 wv[5];
            #pragma unroll
            for (int b = 0; b < 5; ++b)
                wv[b] = *(const float4*)(wp[b] + k);
            #pragma unroll
            for (int a = 0; a < 2; ++a)
                #pragma unroll
                for (int b = 0; b < 5; ++b) {
                    acc[a][b] = fmaf(f[a].x, wv[b].x, acc[a][b]);
                    acc[a][b] = fmaf(f[a].y, wv[b].y, acc[a][b]);
                    acc[a][b] = fmaf(f[a].z, wv[b].z, acc[a][b]);
                    acc[a][b] = fmaf(f[a].w, wv[b].w, acc[a][b]);
                }
        }
        #pragma unroll
        for (int a = 0; a < 2; ++a) {
            unsigned e = sg[h16 + vi + 8 * a];
            if (e == 0xFFFFFFFFu) continue;
            int g  = (int)(e & 8191u);
            int gx = g >> 7, gy = (g >> 2) & 31, gz = g & 3;
            #pragma unroll
            for (int b = 0; b < 5; ++b) {
                if (!tok[b]) continue;
                int cx = gx - (tkx[b] - 3);
                int cy = gy - (tky[b] - 3);
                int cz = gz - (tkz[b] - 1);
                if ((unsigned)cx < (unsigned)GXD && (unsigned)cy < (unsigned)GYD &&
                    (unsigned)cz < (unsigned)GZD)
                    atomicAdd(&sscore[(cx << 7) | (cy << 2) | cz], acc[a][b]);
            }
        }
    }
    __syncthreads();                           // all waves' deposits done
    {   // coalesced partial writeback (covers every cell)
        float* dst = partial + ((size_t)m * NSLC + blockIdx.x) * GCELLS;
        const float4* s4 = (const float4*)sscore;
        float4* d4 = (float4*)dst;
        #pragma unroll
        for (int i = 0; i < GCELLS / 4 / 512; ++i)
            d4[tid + 512 * i] = s4[tid + 512 * i];
    }
}

// argfin: 4 blocks/ROI sum the 12 partials over a 2048-cell chunk, block-argmax,
// u64 atomicMax into best[m]; globally-last block writes all 64 outputs.
__global__ __launch_bounds__(256) void k_argfin(
        const float* __restrict__ partial, const float* __restrict__ rois,
        const float* __restrict__ pbox, unsigned long long* __restrict__ best,
        unsigned* __restrict__ done, float* __restrict__ out) {
    __shared__ unsigned long long red[256];
    __shared__ unsigned lastflag;
    const int tid = threadIdx.x;
    const int m = blockIdx.y;
    const float* base = partial + (size_t)m * NSLC * GCELLS;
    const int c0 = blockIdx.x * (GCELLS / ABLK);
    unsigned long long bk = 0ull;
    #pragma unroll
    for (int i = 0; i < GCELLS / ABLK / 256; ++i) {
        int c = c0 + tid + 256 * i;
        float v = 0.0f;
        #pragma unroll
        for (int s = 0; s < NSLC; ++s) v += base[s * GCELLS + c];
        unsigned ub  = __float_as_uint(v);
        unsigned key = (ub & 0x80000000u) ? ~ub : (ub | 0x80000000u);  // order-preserving
        unsigned long long pk =
            ((unsigned long long)key << 32) | (unsigned)(GCELLS - 1 - c);  // ties -> smallest g
        bk = bk > pk ? bk : pk;
    }
    red[tid] = bk;
    __syncthreads();
    for (int st = 128; st > 0; st >>= 1) {
        if (tid < st) {
            unsigned long long o = red[tid + st];
            if (o > red[tid]) red[tid] = o;
        }
        __syncthreads();
    }
    if (tid == 0) {
        atomicMax(&best[m], red[0]);
        __threadfence();                       // publish before signalling done
        unsigned d = atomicAdd(done, 1u);
        lastflag = (d == ABLK * MROI - 1u);
    }
    __syncthreads();
    if (lastflag && tid < MROI) {
        // atomic read -> sees all prior atomicMax on the same address
        unsigned long long bv = atomicMax(&best[tid], 0ull);
        int g = (GCELLS - 1) - (int)(unsigned)(bv & 0xFFFFFFFFu);
        float X, Y, Z;
        cell_xyz(rois + tid * 7, g, X, Y, Z);
        out[tid * 7 + 0] = X;
        out[tid * 7 + 1] = Y;
        out[tid * 7 + 2] = Z;
        out[tid * 7 + 3] = pbox[3];
        out[tid * 7 + 4] = pbox[4];
        out[tid * 7 + 5] = pbox[5];
        out[tid * 7 + 6] = pbox[6];
    }
}

extern "C" void kernel_launch(void* const* d_in, const int* in_sizes, int n_in,
                              void* d_out, int out_size, void* d_ws, size_t ws_size,
                              hipStream_t stream) {
    const float* rois    = (const float*)d_in[0];
    const float* pbox    = (const float*)d_in[1];
    const float* vfeat   = (const float*)d_in[2];
    const float* fproto  = (const float*)d_in[3];
    const int*   vcoords = (const int*)d_in[4];
    float* out = (float*)d_out;

    // ws layout: v2p | list | partial(12 slices) | best(64 u64) | cnt(64) | done(1)
    int*      v2p     = (int*)d_ws;                              // NGRID ints
    unsigned* list    = (unsigned*)(v2p + NGRID);                // MROI*GCELLS
    float*    partial = (float*)(list + (size_t)MROI * GCELLS);  // 12*MROI*GCELLS floats
    unsigned long long* best =
        (unsigned long long*)(partial + (size_t)NSLC * MROI * GCELLS);
    int*      cnt  = (int*)(best + MROI);                        // 64 ints
    unsigned* done = (unsigned*)(cnt + MROI);                    // 1 uint

    hipMemsetAsync(v2p, 0xFF, (size_t)NGRID * 4, stream);
    k_zbest  <<<1, 64, 0, stream>>>(best, done);
    k_scatter<<<(NVOX + 255) / 256, 256, 0, stream>>>(vcoords, v2p, cnt);
    k_build  <<<dim3(GCELLS / 256, MROI), 256, 0, stream>>>(rois, v2p, list, cnt);
    k_dots   <<<dim3(NSLC, MROI), 512, 0, stream>>>(vfeat, fproto, list, cnt, partial);
    k_argfin <<<dim3(ABLK, MROI), 256, 0, stream>>>(partial, rois, pbox, best, done, out);
}

// Round 8
// 281.660 us; speedup vs baseline: 1.4868x; 1.2808x over previous
//
#include <hip/hip_runtime.h>
#include <stdint.h>

#define GRID_Z 10
#define GRID_Y 400
#define GRID_X 352
#define NGRID (GRID_Z * GRID_Y * GRID_X)   // 1,408,000
#define NVOX 200000
#define CCH 128
#define MROI 64
#define GXD 64
#define GYD 32
#define GZD 4
#define GCELLS 8192                         // GXD*GYD*GZD
#define NTAPS 147                           // 7*7*3
#define TROWS 32                            // voxel rows per tile
#define NSLC 12                             // slices per ROI -> 768 blocks = 3/CU
#define PITCH 136                           // bf16 units per LDS feat row (128+8)
#define NTT 10                              // tap-tiles of 16 (160 padded taps)
#define BFRAGN (NTT * 4 * 64)               // uint4 entries per plane (2560)

typedef short bf16x8 __attribute__((ext_vector_type(8)));
typedef float f32x4 __attribute__((ext_vector_type(4)));

__device__ __forceinline__ unsigned f2bf(float x) {   // RNE fp32->bf16 bits
    unsigned u = __float_as_uint(x);
    return (u + 0x7FFFu + ((u >> 16) & 1u)) >> 16;
}
__device__ __forceinline__ float bf2f(unsigned h) {
    return __uint_as_float(h << 16);
}

// Recompute a grid cell's world xyz exactly like the reference (fp32, no fma
// contraction so floor() boundaries match XLA's mul+add evaluation).
__device__ __forceinline__ void cell_xyz(const float* __restrict__ roi, int g,
                                         float& X, float& Y, float& Z) {
#pragma clang fp contract(off)
    int iz = g & 3;
    int iy = (g >> 2) & 31;
    int ix = g >> 7;
    float bx = roi[3] * 2.0f;   // EXTEND on x,y dims
    float by = roi[4] * 2.0f;
    float bz = roi[5];
    float lx = (ix + 0.5f) / 64.0f * bx - bx / 2.0f;
    float ly = (iy + 0.5f) / 32.0f * by - by / 2.0f;
    float lz = (iz + 0.5f) / 4.0f  * bz - bz / 2.0f;
    float c = cosf(roi[6]);
    float s = sinf(roi[6]);
    X = lx * c + ly * (-s) + roi[0];
    Y = lx * s + ly * c    + roi[1];
    Z = lz + roi[2];
}

__device__ __forceinline__ int cell_to_pidx(const float* __restrict__ roi, int g,
                                            const int* __restrict__ v2p) {
#pragma clang fp contract(off)
    float X, Y, Z;
    cell_xyz(roi, g, X, Y, Z);
    float fx = floorf((X - 0.0f)     / 0.05f);
    float fy = floorf((Y - (-40.0f)) / 0.05f);
    float fz = floorf((Z - (-3.0f))  / 0.1f);
    int cx = (int)floorf(fx / 4.0f);
    int cy = (int)floorf(fy / 4.0f);
    int cz = (int)floorf(fz / 4.0f);
    int p = -1;
    if (cz >= 0 && cz < GRID_Z && cy >= 0 && cy < GRID_Y && cx >= 0 && cx < GRID_X)
        p = v2p[(cz * GRID_Y + cy) * GRID_X + cx];
    return p;
}

// ---------------- phase kernels (stream-ordered) ----------------
// prep: split fproto into (hi, lo) bf16 planes laid out in EXACT mfma B-frag
// order: plane[((tT*4+ks)*64+lane)] = B[k=ks*32+(lane>>4)*8+j][tap=tT*16+(lane&15)]
__global__ void k_prep(const float* __restrict__ fproto,
                       uint4* __restrict__ bH, uint4* __restrict__ bL) {
    int tT   = blockIdx.x;                 // 0..9
    int ks   = threadIdx.x >> 6;           // 0..3
    int lane = threadIdx.x & 63;
    int tap  = tT * 16 + (lane & 15);
    int k0   = ks * 32 + (lane >> 4) * 8;
    unsigned hi[8], lo[8];
    #pragma unroll
    for (int j = 0; j < 8; ++j) {
        float x = (tap < NTAPS) ? fproto[tap * CCH + k0 + j] : 0.0f;
        unsigned h = f2bf(x);
        float r = x - bf2f(h);
        hi[j] = h;
        lo[j] = f2bf(r);
    }
    uint4 uh, ul;
    uh.x = hi[0] | (hi[1] << 16); uh.y = hi[2] | (hi[3] << 16);
    uh.z = hi[4] | (hi[5] << 16); uh.w = hi[6] | (hi[7] << 16);
    ul.x = lo[0] | (lo[1] << 16); ul.y = lo[2] | (lo[3] << 16);
    ul.z = lo[4] | (lo[5] << 16); ul.w = lo[6] | (lo[7] << 16);
    int idx = (tT * 4 + ks) * 64 + lane;
    bH[idx] = uh;
    bL[idx] = ul;
}

__global__ void k_scatter(const int* __restrict__ vcoords, int* __restrict__ v2p,
                          int* __restrict__ cnt) {
    int i = blockIdx.x * 256 + threadIdx.x;
    if (blockIdx.x == 0 && threadIdx.x < MROI) cnt[threadIdx.x] = 0;
    if (i >= NVOX) return;
    int z = vcoords[i * 4 + 1];
    int y = vcoords[i * 4 + 2];
    int x = vcoords[i * 4 + 3];
    atomicMax(&v2p[(z * GRID_Y + y) * GRID_X + x], i);
}

__global__ void k_build(const float* __restrict__ rois, const int* __restrict__ v2p,
                        unsigned* __restrict__ list, int* __restrict__ cnt) {
    int g = blockIdx.x * 256 + threadIdx.x;
    int m = blockIdx.y;
    int lane = threadIdx.x & 63;
    int p = cell_to_pidx(rois + m * 7, g, v2p);
    bool v = p >= 0;
    unsigned long long bal = __ballot(v);
    int nset = __popcll(bal);
    int base = 0;
    if (lane == 0 && nset) base = atomicAdd(&cnt[m], nset);
    base = __shfl(base, 0, 64);
    if (v) {
        int pos = __popcll(bal & ((1ull << lane) - 1ull));
        list[m * GCELLS + base + pos] = ((unsigned)p << 13) | (unsigned)g;
    }
}

// dots: split-bf16 MFMA. 4 waves = 2 row-tiles x 2 tap-halves.
// Per voxel-tile per wave: 8 ds_read_b128 (A hi/lo frags), 40 L2 b128 (B frags),
// 60 mfma_f32_16x16x32_bf16 (ah*bh + ah*bl + al*bh), then R1 deposit loop.
__global__ __launch_bounds__(256) void k_dots(
        const float* __restrict__ vfeat, const uint4* __restrict__ bH,
        const uint4* __restrict__ bL, const unsigned* __restrict__ list,
        const int* __restrict__ cnt, float* __restrict__ partial) {
    __shared__ float sscore[GCELLS];                       // 32 KB
    __shared__ __align__(16) unsigned short sAh[TROWS * PITCH];  // 8.7 KB
    __shared__ __align__(16) unsigned short sAl[TROWS * PITCH];  // 8.7 KB
    __shared__ unsigned sg[TROWS];

    const int m    = blockIdx.y;
    const int tid  = threadIdx.x;
    const int w    = tid >> 6;
    const int lane = tid & 63;
    const int rt   = w >> 1;               // row-tile: rows rt*16..+15
    const int th   = w & 1;                // tap-half: taps th*80..+79
    const int col  = lane & 15;
    const int kg   = lane >> 4;            // k-group 0..3
    const int n    = cnt[m];
    const unsigned* lst = list + m * GCELLS;

    // per-lane tap decode (5 tap-tiles per wave; tap = th*80 + tt*16 + col)
    int tkx[5], tky[5], tkz[5], tok[5];
    #pragma unroll
    for (int tt = 0; tt < 5; ++tt) {
        int t = th * 80 + tt * 16 + col;
        tok[tt] = t < NTAPS;
        int tc = tok[tt] ? t : 0;
        int kx  = tc / 21;
        int rem = tc - kx * 21;
        tkx[tt] = kx; tky[tt] = rem / 3; tkz[tt] = rem - tky[tt] * 3;
    }
    {   // zero the private score tile
        float4* s4 = (float4*)sscore;
        #pragma unroll
        for (int i = 0; i < GCELLS / 4 / 256; ++i)
            s4[tid + 256 * i] = make_float4(0.f, 0.f, 0.f, 0.f);
    }
    for (int vt0 = blockIdx.x * TROWS; vt0 < n; vt0 += TROWS * NSLC) {
        __syncthreads();                   // score-zero / prior deposits done
        {   // stage 32 rows: 8 threads/row, 16 ch each; split fp32 -> (hi,lo) bf16
            int r = tid >> 3, q = tid & 7, v = vt0 + r;
            unsigned e = 0xFFFFFFFFu;
            if (v < n) e = lst[v];
            if (q == 0) sg[r] = e;
            if (e != 0xFFFFFFFFu) {
                int p = (int)(e >> 13);
                const float4* src = (const float4*)(vfeat + (size_t)p * CCH) + q * 4;
                unsigned hb[16], lb[16];
                #pragma unroll
                for (int j = 0; j < 4; ++j) {
                    float4 s = src[j];
                    float xs[4] = {s.x, s.y, s.z, s.w};
                    #pragma unroll
                    for (int c = 0; c < 4; ++c) {
                        unsigned h = f2bf(xs[c]);
                        hb[j * 4 + c] = h;
                        lb[j * 4 + c] = f2bf(xs[c] - bf2f(h));
                    }
                }
                uint4 h0, h1, l0, l1;
                h0.x = hb[0]  | (hb[1]  << 16); h0.y = hb[2]  | (hb[3]  << 16);
                h0.z = hb[4]  | (hb[5]  << 16); h0.w = hb[6]  | (hb[7]  << 16);
                h1.x = hb[8]  | (hb[9]  << 16); h1.y = hb[10] | (hb[11] << 16);
                h1.z = hb[12] | (hb[13] << 16); h1.w = hb[14] | (hb[15] << 16);
                l0.x = lb[0]  | (lb[1]  << 16); l0.y = lb[2]  | (lb[3]  << 16);
                l0.z = lb[4]  | (lb[5]  << 16); l0.w = lb[6]  | (lb[7]  << 16);
                l1.x = lb[8]  | (lb[9]  << 16); l1.y = lb[10] | (lb[11] << 16);
                l1.z = lb[12] | (lb[13] << 16); l1.w = lb[14] | (lb[15] << 16);
                uint4* dh = (uint4*)((char*)sAh + r * (PITCH * 2) + q * 32);
                uint4* dl = (uint4*)((char*)sAl + r * (PITCH * 2) + q * 32);
                dh[0] = h0; dh[1] = h1;
                dl[0] = l0; dl[1] = l1;
            }
        }
        __syncthreads();
        // A fragments: row = rt*16 + col, k = ks*32 + kg*8 + j
        bf16x8 ah[4], al[4];
        const char* abh = (const char*)sAh + (rt * 16 + col) * (PITCH * 2);
        const char* abl = (const char*)sAl + (rt * 16 + col) * (PITCH * 2);
        #pragma unroll
        for (int ks = 0; ks < 4; ++ks) {
            ah[ks] = *(const bf16x8*)(abh + ks * 64 + kg * 16);
            al[ks] = *(const bf16x8*)(abl + ks * 64 + kg * 16);
        }
        f32x4 acc[5];
        #pragma unroll
        for (int tt = 0; tt < 5; ++tt) acc[tt] = (f32x4){0.f, 0.f, 0.f, 0.f};
        #pragma unroll
        for (int tt = 0; tt < 5; ++tt) {
            const int bi = ((th * 5 + tt) * 4) * 64 + lane;
            #pragma unroll
            for (int ks = 0; ks < 4; ++ks) {
                uint4 uh = bH[bi + ks * 64];
                uint4 ul = bL[bi + ks * 64];
                bf16x8 bh = *(bf16x8*)&uh;
                bf16x8 bl = *(bf16x8*)&ul;
                acc[tt] = __builtin_amdgcn_mfma_f32_16x16x32_bf16(ah[ks], bh, acc[tt], 0, 0, 0);
                acc[tt] = __builtin_amdgcn_mfma_f32_16x16x32_bf16(ah[ks], bl, acc[tt], 0, 0, 0);
                acc[tt] = __builtin_amdgcn_mfma_f32_16x16x32_bf16(al[ks], bh, acc[tt], 0, 0, 0);
            }
        }
        // deposit: D[row][tap] with row = rt*16 + kg*4 + rg, tap col fixed per lane
        #pragma unroll
        for (int tt = 0; tt < 5; ++tt) {
            if (!tok[tt]) continue;
            #pragma unroll
            for (int rg = 0; rg < 4; ++rg) {
                unsigned e = sg[rt * 16 + kg * 4 + rg];
                if (e == 0xFFFFFFFFu) continue;
                int g  = (int)(e & 8191u);
                int cx = (g >> 7)        - (tkx[tt] - 3);
                int cy = ((g >> 2) & 31) - (tky[tt] - 3);
                int cz = (g & 3)         - (tkz[tt] - 1);
                if ((unsigned)cx < (unsigned)GXD && (unsigned)cy < (unsigned)GYD &&
                    (unsigned)cz < (unsigned)GZD)
                    atomicAdd(&sscore[(cx << 7) | (cy << 2) | cz], acc[tt][rg]);
            }
        }
    }
    __syncthreads();                       // all waves' deposits done
    {   // coalesced partial writeback (covers every cell)
        float* dst = partial + ((size_t)m * NSLC + blockIdx.x) * GCELLS;
        const float4* s4 = (const float4*)sscore;
        float4* d4 = (float4*)dst;
        #pragma unroll
        for (int i = 0; i < GCELLS / 4 / 256; ++i)
            d4[tid + 256 * i] = s4[tid + 256 * i];
    }
}

// argfin (R1-proven): 64 blocks x 1024 thr, sum 12 partials, argmax, write out.
__global__ __launch_bounds__(1024) void k_argfin(
        const float* __restrict__ partial, const float* __restrict__ rois,
        const float* __restrict__ pbox, float* __restrict__ out) {
    __shared__ unsigned long long red[1024];
    int m = blockIdx.x;
    int tid = threadIdx.x;
    const float* base = partial + (size_t)m * NSLC * GCELLS;
    unsigned long long bk = 0ull;
    #pragma unroll
    for (int i = 0; i < GCELLS / 1024; ++i) {
        int g = tid + 1024 * i;
        float v = 0.0f;
        #pragma unroll
        for (int s = 0; s < NSLC; ++s) v += base[s * GCELLS + g];
        unsigned ub  = __float_as_uint(v);
        unsigned key = (ub & 0x80000000u) ? ~ub : (ub | 0x80000000u);  // order-preserving
        unsigned long long pk =
            ((unsigned long long)key << 32) | (unsigned)(GCELLS - 1 - g);  // ties -> smallest g
        bk = bk > pk ? bk : pk;
    }
    red[tid] = bk;
    __syncthreads();
    for (int s = 512; s > 0; s >>= 1) {
        if (tid < s) {
            unsigned long long o = red[tid + s];
            if (o > red[tid]) red[tid] = o;
        }
        __syncthreads();
    }
    if (tid == 0) {
        int g = (GCELLS - 1) - (int)(unsigned)(red[0] & 0xFFFFFFFFu);
        float X, Y, Z;
        cell_xyz(rois + m * 7, g, X, Y, Z);
        out[m * 7 + 0] = X;
        out[m * 7 + 1] = Y;
        out[m * 7 + 2] = Z;
        out[m * 7 + 3] = pbox[3];
        out[m * 7 + 4] = pbox[4];
        out[m * 7 + 5] = pbox[5];
        out[m * 7 + 6] = pbox[6];
    }
}

extern "C" void kernel_launch(void* const* d_in, const int* in_sizes, int n_in,
                              void* d_out, int out_size, void* d_ws, size_t ws_size,
                              hipStream_t stream) {
    const float* rois    = (const float*)d_in[0];
    const float* pbox    = (const float*)d_in[1];
    const float* vfeat   = (const float*)d_in[2];
    const float* fproto  = (const float*)d_in[3];
    const int*   vcoords = (const int*)d_in[4];
    float* out = (float*)d_out;

    // ws layout: v2p | list | partial(12) | bH | bL | cnt
    int*      v2p     = (int*)d_ws;                              // NGRID ints
    unsigned* list    = (unsigned*)(v2p + NGRID);                // MROI*GCELLS
    float*    partial = (float*)(list + (size_t)MROI * GCELLS);  // 12*MROI*GCELLS floats
    uint4*    bH      = (uint4*)(partial + (size_t)NSLC * MROI * GCELLS);
    uint4*    bL      = bH + BFRAGN;
    int*      cnt     = (int*)(bL + BFRAGN);                     // 64 ints

    hipMemsetAsync(v2p, 0xFF, (size_t)NGRID * 4, stream);
    k_prep   <<<NTT, 256, 0, stream>>>(fproto, bH, bL);
    k_scatter<<<(NVOX + 255) / 256, 256, 0, stream>>>(vcoords, v2p, cnt);
    k_build  <<<dim3(GCELLS / 256, MROI), 256, 0, stream>>>(rois, v2p, list, cnt);
    k_dots   <<<dim3(NSLC, MROI), 256, 0, stream>>>(vfeat, bH, bL, list, cnt, partial);
    k_argfin <<<MROI, 1024, 0, stream>>>(partial, rois, pbox, out);
}